// Round 13
// baseline (224.832 us; speedup 1.0000x reference)
//
#include <hip/hip_runtime.h>
#include <hip/hip_bf16.h>
#include <stdint.h>

// Problem constants
#define NB   32
#define CIN  128
#define HIN  56
#define WIN  56
#define KOUT 256
#define HOUT 54
#define WOUT 54
#define PQ   (HOUT*WOUT)     // 2916
#define NPIX (NB*PQ)         // 93312 = 729 * 128
#define KK   (CIN*9)         // 1152
#define HW   (HIN*WIN)       // 3136
#define TWN_FACTOR 0.05f

typedef short bf16x8 __attribute__((ext_vector_type(8)));   // 8 bf16 = 4 VGPRs
typedef float f32x4  __attribute__((ext_vector_type(4)));

// async global->LDS, 16B/lane; LDS dest = wave-uniform base + lane*16
__device__ __forceinline__ void glds16(const void* g, void* l) {
  __builtin_amdgcn_global_load_lds(
      (__attribute__((address_space(1))) void*)(g),
      (__attribute__((address_space(3))) void*)(l),
      16, 0, 0);
}

__device__ __forceinline__ unsigned pack_bf16(float a, float b) {
  return (unsigned)__bfloat16_as_ushort(__float2bfloat16(a)) |
         ((unsigned)__bfloat16_as_ushort(__float2bfloat16(b)) << 16);
}

// ---- fused prep: blocks [0,288) absmax(|w|); blocks [288,1856) x NCHW->NHWC bf16 ----
__global__ void prep_k(const float* __restrict__ x, const float4* __restrict__ w4,
                       float* __restrict__ amax, __hip_bfloat16* __restrict__ xt) {
  __shared__ __hip_bfloat16 tl[64 * 130 + 32];   // stride 130 (odd dwords)
  __shared__ float sm[4];
  int bid = blockIdx.x;
  int t   = threadIdx.x;

  if (bid < 288) {                               // absmax part (w = 1.18 MB)
    float4 v = w4[bid * 256 + t];
    float m = fmaxf(fmaxf(fabsf(v.x), fabsf(v.y)), fmaxf(fabsf(v.z), fabsf(v.w)));
    #pragma unroll
    for (int off = 32; off > 0; off >>= 1)
      m = fmaxf(m, __shfl_down(m, off));
    int lane = t & 63, wv = t >> 6;
    if (lane == 0) sm[wv] = m;
    __syncthreads();
    if (t == 0)                                  // ws poison 0xAA.. is a tiny negative float
      atomicMax(amax, fmaxf(fmaxf(sm[0], sm[1]), fmaxf(sm[2], sm[3])));
    return;
  }

  int b2 = bid - 288;                            // 0..1567
  int n  = b2 / 49, pc = b2 - n * 49;            // image, 64-pixel chunk
  const float* xb = x + (size_t)n * CIN * HW + pc * 64;
  int f4  = t & 15;                              // pixel group (4 px)
  int cp0 = t >> 4;                              // channel-pair base 0..15
  #pragma unroll
  for (int rd = 0; rd < 4; ++rd) {
    int cp = cp0 + rd * 16;                      // pair index 0..63 -> ch {2cp,2cp+1}
    const float* s0 = xb + (size_t)(2 * cp) * HW + f4 * 4;
    float4 v0 = *(const float4*)(s0);            // 256B/16-lane coalesced segments
    float4 v1 = *(const float4*)(s0 + HW);
    *(unsigned*)&tl[(f4 * 4 + 0) * 130 + 2 * cp] = pack_bf16(v0.x, v1.x);
    *(unsigned*)&tl[(f4 * 4 + 1) * 130 + 2 * cp] = pack_bf16(v0.y, v1.y);
    *(unsigned*)&tl[(f4 * 4 + 2) * 130 + 2 * cp] = pack_bf16(v0.z, v1.z);
    *(unsigned*)&tl[(f4 * 4 + 3) * 130 + 2 * cp] = pack_bf16(v0.w, v1.w);
  }
  __syncthreads();
  int cc = t & 15, p0 = t >> 4;                  // phase 2: b128 reads, 16B stores
  __hip_bfloat16* op = xt + ((size_t)n * HW + pc * 64) * CIN + cc * 8;
  #pragma unroll
  for (int p = p0; p < 64; p += 16)
    *(bf16x8*)(op + (size_t)p * CIN) = *(const bf16x8*)&tl[p * 130 + cc * 8];
}

// ---- quantize OIHW fp32 -> fragment-ordered qA[kc][256][8], kc = rs*16 + (c>>3) ----
__global__ void quant_k(const float* __restrict__ w, const float* __restrict__ amax,
                        __hip_bfloat16* __restrict__ qA) {
  float thr = TWN_FACTOR * (*amax);
  int t  = blockIdx.x * 256 + threadIdx.x;       // < 36864
  int kc = t >> 8, row = t & 255;
  int rs = kc >> 4, c0 = (kc & 15) << 3;
  bf16x8 q;
  #pragma unroll
  for (int j = 0; j < 8; ++j) {
    float v  = w[(size_t)(row * CIN + c0 + j) * 9 + rs];
    float qq = (v > thr) ? 1.f : ((v < -thr) ? -1.f : 0.f);
    q[j] = (short)__bfloat16_as_ushort(__float2bfloat16(qq));
  }
  *(bf16x8*)(qA + (size_t)t * 8) = q;            // 16B coalesced
}

// ---- implicit-GEMM conv: 8-wave phase-split structure (m201-style port) ----
// R12 conclusion: ALL 2-phase variants plateau at ~810 TF == the documented
// m97/2-phase structural ceiling (m131-m141/m233). Escape = phase-split + wave
// role diversity (S5.5 regime gate). This kernel: 512 thr / 8 waves, tile =
// 128 px x 256 kout (729 blocks = NPIX/128 exactly), BK=64, 18 K-tiles.
// Per K-tile t:
//   vmcnt(0)+s_barrier   [drains stage(t): 2 glds issued one FULL tile ago]
//   issue W af x8 (L2, A-first)  |  issue stage X(t+1) x2 glds  |  xf ds_read x8
//   lgkmcnt(0); sched_barrier    [xf ready -- rule-18 fence]
//   setprio(1) MFMA i={0,1} x16 setprio(0)
//   s_barrier                    [pure desync: no mem dep -> miscompile-safe]
//   setprio(1) MFMA i={2,3} x16 setprio(0)
// All waits target step-old loads only. W reads L2 (qA 576KB, L2-resident);
// X in LDS with the R8-proven XOR chunk swizzle (both-sides via source).
__global__ __launch_bounds__(512, 2) void conv_gemm(
    const __hip_bfloat16* __restrict__ xt,
    const __hip_bfloat16* __restrict__ qA,       // [144][256][8] fragment-ordered
    const float* __restrict__ bias,
    float* __restrict__ out) {
  __shared__ char smem[65536];                   // K-loop: 2x16KB X dbuf; epilogue: 64KB

  const int tid  = threadIdx.x;
  const int wave = tid >> 6;                     // 0..7
  const int lane = tid & 63;
  const int quad = lane >> 4;
  const int l16  = lane & 15;

  const int wvm = wave >> 1;                     // kout sub-tile 0..3 (x64)
  const int wvn = wave & 1;                      // px sub-tile 0..1 (x64)
  const int km  = wvm * 64;
  const int wn  = wvn * 64;

  // bijective XCD-chunked remap (nwg=729 = 8*91 + 1)
  const int orig = blockIdx.x;
  const int xcd  = orig & 7;
  const int loc  = orig >> 3;
  const int ptile = (xcd < 1) ? loc : 92 + (xcd - 1) * 91 + loc;
  const int pbase = ptile * 128;

  // X staging: 2 glds16/wave/tile; each glds = 8 rows x 8 chunks (1 KB).
  // dest rows wave*16 + g*8 + (lane>>3); slot (lane&7) holds chunk (lane&7)^(row&7).
  const int r8 = lane >> 3;
  const int ch = lane & 7;
  unsigned boffm[2];
  #pragma unroll
  for (int g = 0; g < 2; ++g) {
    int row  = wave * 16 + g * 8 + r8;
    int prow = pbase + row;
    int n = prow / PQ; int rm = prow - n * PQ;
    int p = rm / WOUT; int q = rm - p * WOUT;
    boffm[g] = (unsigned)(n * HW + p * WIN + q) * CIN + ((unsigned)(ch ^ (row & 7)) << 3);
  }

  // W fragment base offsets (elements): quad*2048 + row*8, row = km + i*16 + l16
  unsigned aoff[4];
  #pragma unroll
  for (int i = 0; i < 4; ++i)
    aoff[i] = (unsigned)(quad * 256 + (km + i * 16 + l16)) * 8;

  f32x4 acc[4][4];
  #pragma unroll
  for (int i = 0; i < 4; ++i)
    #pragma unroll
    for (int j = 0; j < 4; ++j)
      acc[i][j] = (f32x4){0.f, 0.f, 0.f, 0.f};

  // prologue: stage X(0) into buf 0
  {
    char* bdst = smem + wave * 2048;
    #pragma unroll
    for (int g = 0; g < 2; ++g)
      glds16(xt + boffm[g], bdst + g * 1024);
  }

  for (int t = 0; t < 18; ++t) {
    // entry: stage(t) is one full tile old; nothing younger is outstanding.
    asm volatile("s_waitcnt vmcnt(0)" ::: "memory");
    __builtin_amdgcn_s_barrier();
    __builtin_amdgcn_sched_barrier(0);

    // W fragments for the whole tile, issued FIRST (L2-resident qA)
    const unsigned astep = ((unsigned)(t >> 1) * 16 + (unsigned)(t & 1) * 8) * 2048;
    bf16x8 af[8];                                // [i*2+h]
    #pragma unroll
    for (int i = 0; i < 4; ++i)
      #pragma unroll
      for (int h = 0; h < 2; ++h)
        af[i * 2 + h] = *(const bf16x8*)(qA + aoff[i] + astep + (unsigned)h * 4 * 2048);
    __builtin_amdgcn_sched_barrier(0);

    // stage X(t+1) into buf (t+1)&1 (its readers drained before entry barrier)
    if (t < 17) {
      const int tn  = t + 1;
      const int rsn = tn >> 1;
      const int rn  = rsn / 3, sn = rsn - rn * 3;
      const unsigned bst = (unsigned)((rn * WIN + sn) * CIN + (tn & 1) * 64);
      char* bdst = smem + (unsigned)(tn & 1) * 16384 + wave * 2048;
      #pragma unroll
      for (int g = 0; g < 2; ++g)
        glds16(xt + boffm[g] + bst, bdst + g * 1024);
    }
    __builtin_amdgcn_sched_barrier(0);

    // X fragments for the whole tile from buf t&1
    const char* bp = smem + (unsigned)(t & 1) * 16384;
    bf16x8 xf[8];                                // [j*2+h]
    #pragma unroll
    for (int j = 0; j < 4; ++j)
      #pragma unroll
      for (int h = 0; h < 2; ++h) {
        int row = wn + j * 16 + l16;
        xf[j * 2 + h] =
            *(const bf16x8*)(bp + row * 128 + (((h * 4 + quad) ^ (row & 7)) << 4));
      }
    asm volatile("s_waitcnt lgkmcnt(0)" ::: "memory");
    __builtin_amdgcn_sched_barrier(0);           // rule 18: pin MFMA below the wait

    // phase 0: i = {0,1}
    __builtin_amdgcn_s_setprio(1);
    #pragma unroll
    for (int i = 0; i < 2; ++i)
      #pragma unroll
      for (int h = 0; h < 2; ++h)
        #pragma unroll
        for (int j = 0; j < 4; ++j)
          acc[i][j] = __builtin_amdgcn_mfma_f32_16x16x32_bf16(af[i * 2 + h], xf[j * 2 + h],
                                                              acc[i][j], 0, 0, 0);
    __builtin_amdgcn_s_setprio(0);
    __builtin_amdgcn_s_barrier();                // desync fence (no mem dep)

    // phase 1: i = {2,3}
    __builtin_amdgcn_s_setprio(1);
    #pragma unroll
    for (int i = 2; i < 4; ++i)
      #pragma unroll
      for (int h = 0; h < 2; ++h)
        #pragma unroll
        for (int j = 0; j < 4; ++j)
          acc[i][j] = __builtin_amdgcn_mfma_f32_16x16x32_bf16(af[i * 2 + h], xf[j * 2 + h],
                                                              acc[i][j], 0, 0, 0);
    __builtin_amdgcn_s_setprio(0);
  }

  __syncthreads();                               // main loop done; repurpose smem

  // ---- epilogue: per-wave LDS transpose -> k-major float4 stores (128B segments) ----
  // wave-private 8 KB regions; 8 x 8 KB = 64 KB == sizeof(smem).
  {
    float* Sw = (float*)smem + wave * 2048;      // 8 KB per wave
    const int ST  = 65;                          // padded row stride (dwords)
    const int rk  = lane >> 3;                   // 0..7  read row within half
    const int rp  = (lane & 7) * 4;              // 0..28 read pixel base
    const float4* b4 = (const float4*)bias;

    #pragma unroll
    for (int i = 0; i < 4; ++i) {
      float4 bv = b4[(km + i * 16 + quad * 4) >> 2];
      #pragma unroll
      for (int j = 0; j < 4; ++j) {
        Sw[(quad * 4 + 0) * ST + j * 16 + l16] = acc[i][j][0] + bv.x;
        Sw[(quad * 4 + 1) * ST + j * 16 + l16] = acc[i][j][1] + bv.y;
        Sw[(quad * 4 + 2) * ST + j * 16 + l16] = acc[i][j][2] + bv.z;
        Sw[(quad * 4 + 3) * ST + j * 16 + l16] = acc[i][j][3] + bv.w;
      }
      asm volatile("s_waitcnt lgkmcnt(0)" ::: "memory");
      __builtin_amdgcn_sched_barrier(0);
      #pragma unroll
      for (int ri = 0; ri < 2; ++ri) {
        int klocal = ri * 8 + rk;
        int k = km + i * 16 + klocal;
        #pragma unroll
        for (int cg = 0; cg < 2; ++cg) {
          int pixl = cg * 32 + rp;
          float4 v = *(const float4*)&Sw[klocal * ST + pixl];
          int pix = pbase + wn + pixl;
          int n = pix / PQ, pq = pix - n * PQ;   // PQ%4==0, pixl%4==0 -> no straddle
          *(float4*)(out + (size_t)n * (KOUT * PQ) + (size_t)k * PQ + pq) = v;
        }
      }
      asm volatile("s_waitcnt lgkmcnt(0)" ::: "memory");  // reads done before next chunk
      __builtin_amdgcn_sched_barrier(0);
    }
  }
}

extern "C" void kernel_launch(void* const* d_in, const int* in_sizes, int n_in,
                              void* d_out, int out_size, void* d_ws, size_t ws_size,
                              hipStream_t stream) {
  const float* x    = (const float*)d_in[0];
  const float* w    = (const float*)d_in[1];
  const float* bias = (const float*)d_in[2];
  float* out = (float*)d_out;

  // workspace: [0,4) amax float | [256,+25.7MB) xt bf16 | then qA bf16 (576KB)
  float* amax = (float*)d_ws;
  __hip_bfloat16* xt = (__hip_bfloat16*)((char*)d_ws + 256);
  __hip_bfloat16* qA = (__hip_bfloat16*)((char*)d_ws + 256 + (size_t)NB * HW * CIN * 2);

  prep_k  <<<dim3(1856), dim3(256), 0, stream>>>(x, (const float4*)w, amax, xt);
  quant_k <<<dim3(144),  dim3(256), 0, stream>>>(w, amax, qA);
  conv_gemm<<<dim3(729), dim3(512), 0, stream>>>(xt, qA, bias, out);
}

// Round 14
// 196.262 us; speedup vs baseline: 1.1456x; 1.1456x over previous
//
#include <hip/hip_runtime.h>
#include <hip/hip_bf16.h>
#include <stdint.h>

// Problem constants
#define NB   32
#define CIN  128
#define HIN  56
#define WIN  56
#define KOUT 256
#define HOUT 54
#define WOUT 54
#define PQ   (HOUT*WOUT)     // 2916
#define NPIX (NB*PQ)         // 93312
#define KK   (CIN*9)         // 1152
#define HW   (HIN*WIN)       // 3136
#define TWN_FACTOR 0.05f

typedef short bf16x8 __attribute__((ext_vector_type(8)));   // 8 bf16 = 4 VGPRs
typedef float f32x4  __attribute__((ext_vector_type(4)));

// async global->LDS, 16B/lane; LDS dest = wave-uniform base + lane*16
__device__ __forceinline__ void glds16(const void* g, void* l) {
  __builtin_amdgcn_global_load_lds(
      (__attribute__((address_space(1))) void*)(g),
      (__attribute__((address_space(3))) void*)(l),
      16, 0, 0);
}

__device__ __forceinline__ unsigned pack_bf16(float a, float b) {
  return (unsigned)__bfloat16_as_ushort(__float2bfloat16(a)) |
         ((unsigned)__bfloat16_as_ushort(__float2bfloat16(b)) << 16);
}

// ---- fused prep: blocks [0,288) absmax(|w|); blocks [288,1856) x NCHW->NHWC bf16 ----
__global__ void prep_k(const float* __restrict__ x, const float4* __restrict__ w4,
                       float* __restrict__ amax, __hip_bfloat16* __restrict__ xt) {
  __shared__ __hip_bfloat16 tl[64 * 130 + 32];   // stride 130 (odd dwords)
  __shared__ float sm[4];
  int bid = blockIdx.x;
  int t   = threadIdx.x;

  if (bid < 288) {                               // absmax part (w = 1.18 MB)
    float4 v = w4[bid * 256 + t];
    float m = fmaxf(fmaxf(fabsf(v.x), fabsf(v.y)), fmaxf(fabsf(v.z), fabsf(v.w)));
    #pragma unroll
    for (int off = 32; off > 0; off >>= 1)
      m = fmaxf(m, __shfl_down(m, off));
    int lane = t & 63, wv = t >> 6;
    if (lane == 0) sm[wv] = m;
    __syncthreads();
    if (t == 0)                                  // ws poison 0xAA.. is a tiny negative float
      atomicMax(amax, fmaxf(fmaxf(sm[0], sm[1]), fmaxf(sm[2], sm[3])));
    return;
  }

  int b2 = bid - 288;                            // 0..1567
  int n  = b2 / 49, pc = b2 - n * 49;            // image, 64-pixel chunk
  const float* xb = x + (size_t)n * CIN * HW + pc * 64;
  int f4  = t & 15;                              // pixel group (4 px)
  int cp0 = t >> 4;                              // channel-pair base 0..15
  #pragma unroll
  for (int rd = 0; rd < 4; ++rd) {
    int cp = cp0 + rd * 16;                      // pair index 0..63 -> ch {2cp,2cp+1}
    const float* s0 = xb + (size_t)(2 * cp) * HW + f4 * 4;
    float4 v0 = *(const float4*)(s0);            // 256B/16-lane coalesced segments
    float4 v1 = *(const float4*)(s0 + HW);
    *(unsigned*)&tl[(f4 * 4 + 0) * 130 + 2 * cp] = pack_bf16(v0.x, v1.x);
    *(unsigned*)&tl[(f4 * 4 + 1) * 130 + 2 * cp] = pack_bf16(v0.y, v1.y);
    *(unsigned*)&tl[(f4 * 4 + 2) * 130 + 2 * cp] = pack_bf16(v0.z, v1.z);
    *(unsigned*)&tl[(f4 * 4 + 3) * 130 + 2 * cp] = pack_bf16(v0.w, v1.w);
  }
  __syncthreads();
  int cc = t & 15, p0 = t >> 4;                  // phase 2: b128 reads, 16B stores
  __hip_bfloat16* op = xt + ((size_t)n * HW + pc * 64) * CIN + cc * 8;
  #pragma unroll
  for (int p = p0; p < 64; p += 16)
    *(bf16x8*)(op + (size_t)p * CIN) = *(const bf16x8*)&tl[p * 130 + cc * 8];
}

// ---- quantize OIHW fp32 -> fragment-ordered qA[kc][256][8], kc = rs*16 + (c>>3) ----
__global__ void quant_k(const float* __restrict__ w, const float* __restrict__ amax,
                        __hip_bfloat16* __restrict__ qA) {
  float thr = TWN_FACTOR * (*amax);
  int t  = blockIdx.x * 256 + threadIdx.x;       // < 36864
  int kc = t >> 8, row = t & 255;
  int rs = kc >> 4, c0 = (kc & 15) << 3;
  bf16x8 q;
  #pragma unroll
  for (int j = 0; j < 8; ++j) {
    float v  = w[(size_t)(row * CIN + c0 + j) * 9 + rs];
    float qq = (v > thr) ? 1.f : ((v < -thr) ? -1.f : 0.f);
    q[j] = (short)__bfloat16_as_ushort(__float2bfloat16(qq));
  }
  *(bf16x8*)(qA + (size_t)t * 8) = q;            // 16B coalesced
}

// ---- implicit-GEMM conv: 2-buffer LDS (32 KB), guide-verified 2-phase template ----
// BEST VERIFIED (R8: conv 68.0us, MfmaUtil 32.3%, total 195.7us). Campaign:
// R3 3buf-vmcnt 70 | R5 +A-dbuf 69.8 | R8 this 68 | R9 occ-up 83 | R11/12
// BK=128 72.5/73.9 | R13 shallow 8-wave phase-split 95.4. All departures from
// this template lost; 809 TF == the 2-phase structural ceiling (m230/m233).
// Schedule per step t (__syncthreads-fenced; R6 raw-barrier variant raced):
//   __syncthreads()  -- drains G(t)/A(t) (issued a FULL step earlier)
//   issue G(t+1) -> buf (t+1)&1 ; issue A(t+1) -> af[(t+1)&1]
//   compute buf t&1 with af[t&1]  (everything consumed is step-old, zero wait)
__global__ __launch_bounds__(256, 3) void conv_gemm(
    const __hip_bfloat16* __restrict__ xt,
    const __hip_bfloat16* __restrict__ qA,       // [144][256][8] fragment-ordered
    const float* __restrict__ bias,
    float* __restrict__ out) {
  __shared__ __hip_bfloat16 Bs[2][128 * 64];     // 2 x 16 KB, XOR-swizzled 16B chunks

  const int tid  = threadIdx.x;
  const int wave = tid >> 6;
  const int lane = tid & 63;
  const int quad = lane >> 4;
  const int l16  = lane & 15;

  // bijective XCD-chunked remap (nwg=1458 = 8*182 + 2)
  const int orig = blockIdx.x;
  const int xcd  = orig & 7;
  const int loc  = orig >> 3;
  const int bid  = (xcd < 2) ? xcd * 183 + loc
                             : 366 + (xcd - 2) * 182 + loc;

  const int ktile = bid & 1;
  const int ptile = bid >> 1;
  const int k0    = ktile * 128;
  const int pbase = ptile * 128;

  const int wm = (wave >> 1) * 64;               // k_out sub-tile
  const int wn = (wave & 1) * 64;                // pixel sub-tile

  // B staging: 4 glds16/wave/step; each glds = 8 rows x 8 chunks (1 KB).
  const int r8 = lane >> 3;
  const int ch = lane & 7;
  unsigned boffm[4];
  #pragma unroll
  for (int m = 0; m < 4; ++m) {
    int row  = wave * 32 + m * 8 + r8;
    int prow = pbase + row;
    int n = prow / PQ; int rm = prow - n * PQ;
    int p = rm / WOUT; int q = rm - p * WOUT;
    boffm[m] = (unsigned)(n * HW + p * WIN + q) * CIN + ((ch ^ (row & 7)) << 3);
  }

  // A fragment base offsets (elements): quad*2048 + row*8
  unsigned aoff[4];
  #pragma unroll
  for (int i = 0; i < 4; ++i)
    aoff[i] = (unsigned)(quad * 256 + (k0 + wm + i * 16 + l16)) * 8;

  f32x4 acc[4][4];
  #pragma unroll
  for (int i = 0; i < 4; ++i)
    #pragma unroll
    for (int j = 0; j < 4; ++j)
      acc[i][j] = (f32x4){0.f, 0.f, 0.f, 0.f};

  bf16x8 af[2][8];                               // A reg double-buffer [parity][h*4+i]

  // prologue: G(0) into buf 0, A(0) into af[0]; drained by step-0 __syncthreads
  {
    char* bdst0 = (char*)Bs + wave * 4096;
    #pragma unroll
    for (int m = 0; m < 4; ++m)
      glds16(xt + boffm[m], bdst0 + m * 1024);             // G(0)
    #pragma unroll
    for (int h = 0; h < 2; ++h)
      #pragma unroll
      for (int i = 0; i < 4; ++i)
        af[0][h * 4 + i] = *(const bf16x8*)(qA + aoff[i] + (unsigned)h * 4 * 2048);  // A(0)
  }

  #pragma unroll
  for (int t = 0; t < 18; ++t) {
    // Full fence + drain of G(t)/A(t) (both issued one whole step earlier).
    __syncthreads();

    // issue G(t+1) FIRST (max lead time) into buf (t+1)&1
    if (t < 17) {
      const int tn  = t + 1;
      const int rsn = tn >> 1;
      const int rn  = rsn / 3, sn = rsn - rn * 3;
      const unsigned bst = (unsigned)((rn * WIN + sn) * CIN + (tn & 1) * 64);
      char* bdst = (char*)Bs + (unsigned)(tn & 1) * 16384 + wave * 4096;
      #pragma unroll
      for (int m = 0; m < 4; ++m)
        glds16(xt + boffm[m] + bst, bdst + m * 1024);
    }
    __builtin_amdgcn_sched_barrier(0);

    // issue A(t+1) -> other register bank (fully unrolled, static index)
    if (t < 17) {
      const int tn = t + 1;
      const unsigned astep = ((unsigned)(tn >> 1) * 16 + (unsigned)(tn & 1) * 8) * 2048;
      #pragma unroll
      for (int h = 0; h < 2; ++h)
        #pragma unroll
        for (int i = 0; i < 4; ++i)
          af[tn & 1][h * 4 + i] =
              *(const bf16x8*)(qA + aoff[i] + astep + (unsigned)h * 4 * 2048);
    }
    __builtin_amdgcn_sched_barrier(0);

    // compute on buf t&1 with A(t) from registers
    const char* bp = (const char*)Bs + (unsigned)(t & 1) * 16384;
    #pragma unroll
    for (int h = 0; h < 2; ++h) {
      bf16x8 bfr[4];
      #pragma unroll
      for (int i = 0; i < 4; ++i) {
        int row = wn + i * 16 + l16;
        bfr[i] = *(const bf16x8*)(bp + (row * 64 + (((h * 4 + quad) ^ (row & 7)) << 3)) * 2);
      }
      #pragma unroll
      for (int i = 0; i < 4; ++i)
        #pragma unroll
        for (int j = 0; j < 4; ++j)
          acc[i][j] = __builtin_amdgcn_mfma_f32_16x16x32_bf16(af[t & 1][h * 4 + i], bfr[j],
                                                              acc[i][j], 0, 0, 0);
    }
  }

  __syncthreads();                               // main loop done; repurpose Bs

  // ---- epilogue: per-wave LDS transpose -> k-major float4 stores (128B segments) ----
  // wave-private 8 KB regions; 4 x 8 KB = 32 KB == sizeof(Bs).
  {
    float* Sw = (float*)Bs + wave * 2048;        // 8 KB per wave
    const int ST  = 65;                          // padded row stride (dwords)
    const int rk  = lane >> 3;                   // 0..7  read row within half
    const int rp  = (lane & 7) * 4;              // 0..28 read pixel base
    const float4* b4 = (const float4*)bias;

    #pragma unroll
    for (int i = 0; i < 4; ++i) {
      float4 bv = b4[(k0 + wm + i * 16 + quad * 4) >> 2];
      #pragma unroll
      for (int j = 0; j < 4; ++j) {
        Sw[(quad * 4 + 0) * ST + j * 16 + l16] = acc[i][j][0] + bv.x;
        Sw[(quad * 4 + 1) * ST + j * 16 + l16] = acc[i][j][1] + bv.y;
        Sw[(quad * 4 + 2) * ST + j * 16 + l16] = acc[i][j][2] + bv.z;
        Sw[(quad * 4 + 3) * ST + j * 16 + l16] = acc[i][j][3] + bv.w;
      }
      asm volatile("s_waitcnt lgkmcnt(0)" ::: "memory");
      __builtin_amdgcn_sched_barrier(0);
      #pragma unroll
      for (int ri = 0; ri < 2; ++ri) {
        int klocal = ri * 8 + rk;
        int k = k0 + wm + i * 16 + klocal;
        #pragma unroll
        for (int cg = 0; cg < 2; ++cg) {
          int pixl = cg * 32 + rp;
          float4 v = *(const float4*)&Sw[klocal * ST + pixl];
          int pix = pbase + wn + pixl;
          int n = pix / PQ, pq = pix - n * PQ;   // PQ%4==0, pixl%4==0 -> no straddle
          *(float4*)(out + (size_t)n * (KOUT * PQ) + (size_t)k * PQ + pq) = v;
        }
      }
      asm volatile("s_waitcnt lgkmcnt(0)" ::: "memory");  // reads done before next chunk
      __builtin_amdgcn_sched_barrier(0);
    }
  }
}

extern "C" void kernel_launch(void* const* d_in, const int* in_sizes, int n_in,
                              void* d_out, int out_size, void* d_ws, size_t ws_size,
                              hipStream_t stream) {
  const float* x    = (const float*)d_in[0];
  const float* w    = (const float*)d_in[1];
  const float* bias = (const float*)d_in[2];
  float* out = (float*)d_out;

  // workspace: [0,4) amax float | [256,+25.7MB) xt bf16 | then qA bf16 (576KB)
  float* amax = (float*)d_ws;
  __hip_bfloat16* xt = (__hip_bfloat16*)((char*)d_ws + 256);
  __hip_bfloat16* qA = (__hip_bfloat16*)((char*)d_ws + 256 + (size_t)NB * HW * CIN * 2);

  prep_k  <<<dim3(1856), dim3(256), 0, stream>>>(x, (const float4*)w, amax, xt);
  quant_k <<<dim3(144),  dim3(256), 0, stream>>>(w, amax, qA);
  conv_gemm<<<dim3(1458), dim3(256), 0, stream>>>(xt, qA, bias, out);
}